// Round 2
// baseline (275.037 us; speedup 1.0000x reference)
//
#include <hip/hip_runtime.h>

// QattenNet: B=E*T=8192, S=256, A=32, O=128, QH1=128, QD=64, C1=128, H=4.
// Algebra: out[b] = sum_a q[b,a] * (f[b,a,:]·v[b,:]) + beta[b]*sumq[b] + c[b]
//   v[b,o]  = sum_k WkT[k,o] * emb[b,k],  WkT[k,o] = sum_h Wk[h,o,k]
//   emb     = relu(s@Wq1+bq1) @ Wq2 + bq2
//   beta[b] = emb[b,:]·bkSum,             bkSum[k] = sum_h bk[h,k]
//   c[b]    = relu(s@Wc1+bc1)·Wc2 + bc2
//
// R2: split into MLP kernel (VALU-bound, 1 block/CU, big register tiles) and
// stream kernel (memory-bound, 13KB LDS -> 4 blocks/CU, 16 waves/CU).

static constexpr int Sd  = 256;
static constexpr int Ad  = 32;
static constexpr int Od  = 128;
static constexpr int QDd = 64;

// d_ws float offsets
static constexpr size_t WS_WKT   = 0;        // 64*128
static constexpr size_t WS_BKSUM = 8192;     // 64
static constexpr size_t WS_BIAS  = 8256;     // 8192
static constexpr size_t WS_V     = 16448;    // 8192*128 (16B-aligned: 16448*4=65792)

__global__ void qatten_prep(const float* __restrict__ Wk, const float* __restrict__ bk,
                            float* __restrict__ WkT, float* __restrict__ bkSum)
{
    int idx = blockIdx.x * 256 + threadIdx.x;   // 0..8191
    int k = idx >> 7;          // 0..63
    int o = idx & 127;         // 0..127
    float s = 0.f;
#pragma unroll
    for (int h = 0; h < 4; ++h) s += Wk[h * (Od * QDd) + o * QDd + k];
    WkT[k * Od + o] = s;
    if (idx < QDd) {
        float t = 0.f;
#pragma unroll
        for (int h = 0; h < 4; ++h) t += bk[h * QDd + idx];
        bkSum[idx] = t;
    }
}

__global__ __launch_bounds__(256) void qatten_mlp(
    const float* __restrict__ qv, const float* __restrict__ st,
    const float* __restrict__ Wq1, const float* __restrict__ bq1,
    const float* __restrict__ Wq2, const float* __restrict__ bq2,
    const float* __restrict__ Wc1, const float* __restrict__ bc1,
    const float* __restrict__ Wc2, const float* __restrict__ bc2,
    const float* __restrict__ WkT, const float* __restrict__ bkSum,
    float* __restrict__ v_ws, float* __restrict__ bias_ws)
{
    __shared__ float s_lds[32][Sd];     // 32 KB
    __shared__ float h_lds[32][260];    // 33.3 KB (pad +4 keeps row offsets off same bank; cols 0-127 h1, 128-255 hc)
    __shared__ float emb_lds[32][QDd];  // 8 KB      total ~72.5 KB

    const int tid = threadIdx.x;
    const int b0 = blockIdx.x * 32;

    // ---- stage s (32 rows x 256) coalesced ----
    {
        const float4* sp = (const float4*)(st + (size_t)b0 * Sd);
        float4* sl = (float4*)&s_lds[0][0];
#pragma unroll
        for (int i = 0; i < 8; ++i) sl[tid + i * 256] = sp[tid + i * 256];
    }
    __syncthreads();

    // ---- phase 2: h = relu(s @ [Wq1|Wc1] + [bq1|bc1]), 32 rows x 256 cols, K=256 ----
    // thread = 16 rows x 2 cols; s read is a wave-wide LDS broadcast (free).
    {
        const int jq = tid & 127;      // col pair index
        const int rg = tid >> 7;       // 0..1 -> rows rg*16..+15
        const int c2 = jq * 2;
        const float* W  = (c2 < 128) ? (Wq1 + c2) : (Wc1 + (c2 - 128));
        const float* bb = (c2 < 128) ? (bq1 + c2) : (bc1 + (c2 - 128));
        float acc0[16], acc1[16];
#pragma unroll
        for (int r = 0; r < 16; ++r) { acc0[r] = 0.f; acc1[r] = 0.f; }
        for (int i = 0; i < Sd; i += 4) {
            const float2 w0 = *(const float2*)(W + (size_t)(i + 0) * 128);
            const float2 w1 = *(const float2*)(W + (size_t)(i + 1) * 128);
            const float2 w2 = *(const float2*)(W + (size_t)(i + 2) * 128);
            const float2 w3 = *(const float2*)(W + (size_t)(i + 3) * 128);
#pragma unroll
            for (int r = 0; r < 16; ++r) {
                const float4 sv = *(const float4*)&s_lds[rg * 16 + r][i];
                float a0 = acc0[r], a1 = acc1[r];
                a0 = fmaf(sv.x, w0.x, a0);  a1 = fmaf(sv.x, w0.y, a1);
                a0 = fmaf(sv.y, w1.x, a0);  a1 = fmaf(sv.y, w1.y, a1);
                a0 = fmaf(sv.z, w2.x, a0);  a1 = fmaf(sv.z, w2.y, a1);
                a0 = fmaf(sv.w, w3.x, a0);  a1 = fmaf(sv.w, w3.y, a1);
                acc0[r] = a0; acc1[r] = a1;
            }
        }
        const float bv0 = bb[0], bv1 = bb[1];
#pragma unroll
        for (int r = 0; r < 16; ++r) {
            float2 hv;
            hv.x = fmaxf(acc0[r] + bv0, 0.f);
            hv.y = fmaxf(acc1[r] + bv1, 0.f);
            *(float2*)&h_lds[rg * 16 + r][c2] = hv;
        }
    }
    __syncthreads();

    // ---- phase 3: emb = h1 @ Wq2 + bq2, 32 rows x 64 cols, K=128 ----
    // thread = 2 rows x 4 cols
    {
        const int jq = tid & 15;       // col quad
        const int rg = tid >> 4;       // 0..15 -> rows rg*2..+1
        const int c4 = jq * 4;
        float acc[2][4] = {};
        for (int i = 0; i < 128; i += 4) {
            const float4 w0 = *(const float4*)(Wq2 + (size_t)(i + 0) * 64 + c4);
            const float4 w1 = *(const float4*)(Wq2 + (size_t)(i + 1) * 64 + c4);
            const float4 w2 = *(const float4*)(Wq2 + (size_t)(i + 2) * 64 + c4);
            const float4 w3 = *(const float4*)(Wq2 + (size_t)(i + 3) * 64 + c4);
#pragma unroll
            for (int r = 0; r < 2; ++r) {
                const float4 hv = *(const float4*)&h_lds[rg * 2 + r][i];
                acc[r][0] = fmaf(hv.x, w0.x, acc[r][0]);
                acc[r][1] = fmaf(hv.x, w0.y, acc[r][1]);
                acc[r][2] = fmaf(hv.x, w0.z, acc[r][2]);
                acc[r][3] = fmaf(hv.x, w0.w, acc[r][3]);
                acc[r][0] = fmaf(hv.y, w1.x, acc[r][0]);
                acc[r][1] = fmaf(hv.y, w1.y, acc[r][1]);
                acc[r][2] = fmaf(hv.y, w1.z, acc[r][2]);
                acc[r][3] = fmaf(hv.y, w1.w, acc[r][3]);
                acc[r][0] = fmaf(hv.z, w2.x, acc[r][0]);
                acc[r][1] = fmaf(hv.z, w2.y, acc[r][1]);
                acc[r][2] = fmaf(hv.z, w2.z, acc[r][2]);
                acc[r][3] = fmaf(hv.z, w2.w, acc[r][3]);
                acc[r][0] = fmaf(hv.w, w3.x, acc[r][0]);
                acc[r][1] = fmaf(hv.w, w3.y, acc[r][1]);
                acc[r][2] = fmaf(hv.w, w3.z, acc[r][2]);
                acc[r][3] = fmaf(hv.w, w3.w, acc[r][3]);
            }
        }
        const float4 bias = *(const float4*)(bq2 + c4);
#pragma unroll
        for (int r = 0; r < 2; ++r) {
            float4 ev;
            ev.x = acc[r][0] + bias.x;
            ev.y = acc[r][1] + bias.y;
            ev.z = acc[r][2] + bias.z;
            ev.w = acc[r][3] + bias.w;
            *(float4*)&emb_lds[rg * 2 + r][c4] = ev;
        }
    }
    __syncthreads();

    // ---- phase 4: v = emb @ WkT, 32 rows x 128 cols, K=64 -> global ws ----
    // thread = 8 rows x 2 cols; emb read is wave-wide broadcast.
    {
        const int jq = tid & 63;
        const int rg = tid >> 6;       // 0..3 -> rows rg*8..+7
        const int c2 = jq * 2;
        float acc0[8], acc1[8];
#pragma unroll
        for (int r = 0; r < 8; ++r) { acc0[r] = 0.f; acc1[r] = 0.f; }
        for (int i = 0; i < QDd; i += 4) {
            const float2 w0 = *(const float2*)(WkT + (size_t)(i + 0) * 128 + c2);
            const float2 w1 = *(const float2*)(WkT + (size_t)(i + 1) * 128 + c2);
            const float2 w2 = *(const float2*)(WkT + (size_t)(i + 2) * 128 + c2);
            const float2 w3 = *(const float2*)(WkT + (size_t)(i + 3) * 128 + c2);
#pragma unroll
            for (int r = 0; r < 8; ++r) {
                const float4 ev = *(const float4*)&emb_lds[rg * 8 + r][i];
                float a0 = acc0[r], a1 = acc1[r];
                a0 = fmaf(ev.x, w0.x, a0);  a1 = fmaf(ev.x, w0.y, a1);
                a0 = fmaf(ev.y, w1.x, a0);  a1 = fmaf(ev.y, w1.y, a1);
                a0 = fmaf(ev.z, w2.x, a0);  a1 = fmaf(ev.z, w2.y, a1);
                a0 = fmaf(ev.w, w3.x, a0);  a1 = fmaf(ev.w, w3.y, a1);
                acc0[r] = a0; acc1[r] = a1;
            }
        }
#pragma unroll
        for (int r = 0; r < 8; ++r) {
            float2 vv; vv.x = acc0[r]; vv.y = acc1[r];
            *(float2*)(v_ws + (size_t)(b0 + rg * 8 + r) * 128 + c2) = vv;
        }
    }

    // ---- phase 5: bias[b] = c[b] + beta[b]*sumq[b]  (8 lanes per b; no sync needed:
    //      reads emb_lds (synced after ph3) and h_lds cols 128+ (synced after ph2)) ----
    {
        const int b = tid >> 3;        // 0..31
        const int i = tid & 7;
        float pb = 0.f, pc = 0.f, pq = 0.f;
#pragma unroll
        for (int k = i; k < QDd; k += 8)  pb = fmaf(emb_lds[b][k], bkSum[k], pb);
#pragma unroll
        for (int j = i; j < 128; j += 8)  pc = fmaf(h_lds[b][128 + j], Wc2[j], pc);
#pragma unroll
        for (int a = i; a < Ad; a += 8)   pq += qv[(size_t)(b0 + b) * Ad + a];
#pragma unroll
        for (int d = 4; d >= 1; d >>= 1) {
            pb += __shfl_down(pb, d, 8);
            pc += __shfl_down(pc, d, 8);
            pq += __shfl_down(pq, d, 8);
        }
        if (i == 0) bias_ws[b0 + b] = (pc + bc2[0]) + pb * pq;
    }
}

__global__ __launch_bounds__(256) void qatten_stream(
    const float* __restrict__ qv, const float* __restrict__ fs,
    const float* __restrict__ v_ws, const float* __restrict__ bias_ws,
    float* __restrict__ out)
{
    __shared__ float v_lds[8][Od];      // 4 KB
    __shared__ float q_lds[8][Ad];      // 1 KB
    __shared__ float part_lds[8][256];  // 8 KB   total ~13.25 KB -> 4+ blocks/CU

    const int tid = threadIdx.x;
    const int b0 = blockIdx.x * 8;

    // stage v (1024 floats) and q (256 floats)
    ((float4*)&v_lds[0][0])[tid] = ((const float4*)(v_ws + (size_t)b0 * Od))[tid];
    (&q_lds[0][0])[tid] = qv[(size_t)b0 * Ad + tid];
    __syncthreads();

    // stream f: thread = (oq = float4 slot over O, ag = agent group)
    {
        const int oq = tid & 31;
        const int ag = tid >> 5;       // 0..7
        float acc[8];
#pragma unroll
        for (int b = 0; b < 8; ++b) {
            const float4* fb = (const float4*)(fs + (size_t)(b0 + b) * (Ad * Od));
            const float4 v4 = *(const float4*)&v_lds[b][oq * 4];
            float s = 0.f;
#pragma unroll
            for (int r = 0; r < 4; ++r) {
                const int a = ag + 8 * r;
                const float4 f4 = fb[a * 32 + oq];
                float d = f4.x * v4.x;
                d = fmaf(f4.y, v4.y, d);
                d = fmaf(f4.z, v4.z, d);
                d = fmaf(f4.w, v4.w, d);
                s = fmaf(q_lds[b][a], d, s);
            }
            acc[b] = s;
        }
#pragma unroll
        for (int b = 0; b < 8; ++b) part_lds[b][tid] = acc[b];
    }
    __syncthreads();

    // reduce 256 partials per b
    {
        const int b = tid >> 5;        // 0..7
        const int i = tid & 31;
        float sum = 0.f;
#pragma unroll
        for (int c = i; c < 256; c += 32) sum += part_lds[b][c];
#pragma unroll
        for (int d = 16; d >= 1; d >>= 1) sum += __shfl_down(sum, d, 32);
        if (i == 0) out[b0 + b] = sum + bias_ws[b0 + b];
    }
}

extern "C" void kernel_launch(void* const* d_in, const int* in_sizes, int n_in,
                              void* d_out, int out_size, void* d_ws, size_t ws_size,
                              hipStream_t stream) {
    const float* qv  = (const float*)d_in[0];
    const float* st  = (const float*)d_in[1];
    const float* fs  = (const float*)d_in[2];
    const float* Wq1 = (const float*)d_in[3];
    const float* bq1 = (const float*)d_in[4];
    const float* Wq2 = (const float*)d_in[5];
    const float* bq2 = (const float*)d_in[6];
    const float* Wk  = (const float*)d_in[7];
    const float* bk  = (const float*)d_in[8];
    const float* Wc1 = (const float*)d_in[9];
    const float* bc1 = (const float*)d_in[10];
    const float* Wc2 = (const float*)d_in[11];
    const float* bc2 = (const float*)d_in[12];
    float* out = (float*)d_out;

    float* ws      = (float*)d_ws;
    float* WkT     = ws + WS_WKT;
    float* bkSum   = ws + WS_BKSUM;
    float* bias_ws = ws + WS_BIAS;
    float* v_ws    = ws + WS_V;

    qatten_prep<<<32, 256, 0, stream>>>(Wk, bk, WkT, bkSum);
    qatten_mlp<<<256, 256, 0, stream>>>(qv, st, Wq1, bq1, Wq2, bq2,
                                        Wc1, bc1, Wc2, bc2, WkT, bkSum,
                                        v_ws, bias_ws);
    qatten_stream<<<1024, 256, 0, stream>>>(qv, fs, v_ws, bias_ws, out);
}

// Round 3
// 246.603 us; speedup vs baseline: 1.1153x; 1.1153x over previous
//
#include <hip/hip_runtime.h>

// QattenNet: B=E*T=8192, S=256, A=32, O=128, QH1=128, QD=64, C1=128, H=4.
// Algebra: out[b] = sum_a q[b,a] * (f[b,a,:]·v[b,:]) + beta[b]*sumq[b] + c[b]
//   v[b,o]  = sum_k WkT[k,o] * emb[b,k],  WkT[k,o] = sum_h Wk[h,o,k]
//   emb     = relu(s@Wq1+bq1) @ Wq2 + bq2
//   beta[b] = emb[b,:]·bkSum,             bkSum[k] = sum_h bk[h,k]
//   c[b]    = relu(s@Wc1+bc1)·Wc2 + bc2
//
// R3: single fused kernel, NB=8 rows/block, grid=1024, LDS 23.3 KB ->
// 4 blocks/CU resident (16 waves/CU, 4 waves/SIMD). R1 failed at 2 blocks/CU
// (64 KB LDS) and R2's split mlp kernel ran at 1 wave/SIMD (latency-exposed).

static constexpr int Sd  = 256;
static constexpr int Ad  = 32;
static constexpr int Od  = 128;
static constexpr int QDd = 64;
static constexpr int NB  = 8;

__global__ void qatten_prep(const float* __restrict__ Wk, const float* __restrict__ bk,
                            float* __restrict__ WkT, float* __restrict__ bkSum)
{
    int idx = blockIdx.x * 256 + threadIdx.x;   // 0..8191
    int k = idx >> 7;          // 0..63
    int o = idx & 127;         // 0..127
    float s = 0.f;
#pragma unroll
    for (int h = 0; h < 4; ++h) s += Wk[h * (Od * QDd) + o * QDd + k];
    WkT[k * Od + o] = s;
    if (idx < QDd) {
        float t = 0.f;
#pragma unroll
        for (int h = 0; h < 4; ++h) t += bk[h * QDd + idx];
        bkSum[idx] = t;
    }
}

__global__ __launch_bounds__(256, 4) void qatten_fused(
    const float* __restrict__ qv, const float* __restrict__ st, const float* __restrict__ fs,
    const float* __restrict__ Wq1, const float* __restrict__ bq1,
    const float* __restrict__ Wq2, const float* __restrict__ bq2,
    const float* __restrict__ Wc1, const float* __restrict__ bc1,
    const float* __restrict__ Wc2, const float* __restrict__ bc2,
    const float* __restrict__ WkT, const float* __restrict__ bkSum,
    float* __restrict__ out)
{
    __shared__ float s_lds[NB][Sd];     // 8 KB
    __shared__ float h_lds[NB][260];    // 8.125 KB (cols 0-127: h1, 128-255: hc)
    __shared__ float emb_lds[NB][QDd];  // 2 KB
    __shared__ float v_lds[NB][Od];     // 4 KB
    __shared__ float q_lds[NB][Ad];     // 1 KB
    __shared__ float red_lds[NB][4];    // 128 B
    __shared__ float bias_lds[NB];      // 32 B   total ~23.3 KB

    const int tid = threadIdx.x;
    const int b0 = blockIdx.x * NB;

    // ---- phase 0: stage s (8x256) and q (8x32), coalesced ----
    {
        const float4* sp = (const float4*)(st + (size_t)b0 * Sd);
        float4* sl = (float4*)&s_lds[0][0];
        sl[tid] = sp[tid];
        sl[tid + 256] = sp[tid + 256];
        (&q_lds[0][0])[tid] = qv[(size_t)b0 * Ad + tid];
    }
    __syncthreads();

    // ---- phase 2: h = relu(s @ [Wq1|Wc1] + [bq1|bc1]); thread = 1 col x 8 rows ----
    // weight loads coalesced across lanes (consecutive cols); s is wave-uniform
    // LDS broadcast. Waves 0-1 -> Wq1 cols, waves 2-3 -> Wc1 cols (wave-uniform).
    {
        const float* W  = (tid < 128) ? (Wq1 + tid) : (Wc1 + (tid - 128));
        const float  bb = (tid < 128) ? bq1[tid] : bc1[tid - 128];
        float acc[NB];
#pragma unroll
        for (int r = 0; r < NB; ++r) acc[r] = 0.f;
#pragma unroll 4
        for (int i = 0; i < Sd; i += 4) {
            const float w0 = W[(size_t)(i + 0) * 128];
            const float w1 = W[(size_t)(i + 1) * 128];
            const float w2 = W[(size_t)(i + 2) * 128];
            const float w3 = W[(size_t)(i + 3) * 128];
#pragma unroll
            for (int r = 0; r < NB; ++r) {
                const float4 sv = *(const float4*)&s_lds[r][i];
                float a = acc[r];
                a = fmaf(sv.x, w0, a);
                a = fmaf(sv.y, w1, a);
                a = fmaf(sv.z, w2, a);
                a = fmaf(sv.w, w3, a);
                acc[r] = a;
            }
        }
#pragma unroll
        for (int r = 0; r < NB; ++r)
            h_lds[r][tid] = fmaxf(acc[r] + bb, 0.f);
    }
    __syncthreads();

    // ---- phase 3: emb = h1 @ Wq2 + bq2; thread = 1 col x 2 rows ----
    {
        const int k = tid & 63;
        const int rg = tid >> 6;        // 0..3 -> rows rg, rg+4
        float a0 = 0.f, a1 = 0.f;
#pragma unroll 4
        for (int j = 0; j < 128; j += 4) {
            const float w0 = Wq2[(size_t)(j + 0) * 64 + k];
            const float w1 = Wq2[(size_t)(j + 1) * 64 + k];
            const float w2 = Wq2[(size_t)(j + 2) * 64 + k];
            const float w3 = Wq2[(size_t)(j + 3) * 64 + k];
            const float4 h0 = *(const float4*)&h_lds[rg][j];
            const float4 h1 = *(const float4*)&h_lds[rg + 4][j];
            a0 = fmaf(h0.x, w0, a0);  a1 = fmaf(h1.x, w0, a1);
            a0 = fmaf(h0.y, w1, a0);  a1 = fmaf(h1.y, w1, a1);
            a0 = fmaf(h0.z, w2, a0);  a1 = fmaf(h1.z, w2, a1);
            a0 = fmaf(h0.w, w3, a0);  a1 = fmaf(h1.w, w3, a1);
        }
        const float bias = bq2[k];
        emb_lds[rg][k] = a0 + bias;
        emb_lds[rg + 4][k] = a1 + bias;
    }
    __syncthreads();

    // ---- phase 4: v = emb @ WkT; thread = 1 col x 4 rows ----
    {
        const int o = tid & 127;
        const int rg = (tid >> 7) * 4;  // rows rg..rg+3
        float acc[4] = {0.f, 0.f, 0.f, 0.f};
#pragma unroll 4
        for (int k = 0; k < QDd; k += 4) {
            const float w0 = WkT[(size_t)(k + 0) * 128 + o];
            const float w1 = WkT[(size_t)(k + 1) * 128 + o];
            const float w2 = WkT[(size_t)(k + 2) * 128 + o];
            const float w3 = WkT[(size_t)(k + 3) * 128 + o];
#pragma unroll
            for (int r = 0; r < 4; ++r) {
                const float4 ev = *(const float4*)&emb_lds[rg + r][k];
                float a = acc[r];
                a = fmaf(ev.x, w0, a);
                a = fmaf(ev.y, w1, a);
                a = fmaf(ev.z, w2, a);
                a = fmaf(ev.w, w3, a);
                acc[r] = a;
            }
        }
#pragma unroll
        for (int r = 0; r < 4; ++r) v_lds[rg + r][o] = acc[r];
    }

    // ---- phase 5: bias[b] = c[b] + beta[b]*sumq[b]; 32 lanes per b ----
    // reads emb_lds (valid after ph3 sync) and h_lds cols 128+ (valid after ph2).
    {
        const int b = tid >> 5;         // 0..7
        const int i = tid & 31;
        float pb = 0.f, pc = 0.f;
#pragma unroll
        for (int k = i; k < QDd; k += 32)  pb = fmaf(emb_lds[b][k], bkSum[k], pb);
#pragma unroll
        for (int j = i; j < 128; j += 32)  pc = fmaf(h_lds[b][128 + j], Wc2[j], pc);
        float pq = q_lds[b][i];
#pragma unroll
        for (int d = 16; d >= 1; d >>= 1) {
            pb += __shfl_down(pb, d, 32);
            pc += __shfl_down(pc, d, 32);
            pq += __shfl_down(pq, d, 32);
        }
        if (i == 0) bias_lds[b] = (pc + bc2[0]) + pb * pq;
    }
    __syncthreads();

    // ---- phase 6: stream f; acc[b] = sum over my (a,o4) of q[b,a]*(f4·v4) ----
    {
        const int oq = tid & 31;        // float4 slot over O
        const int ag = tid >> 5;        // 0..7
        float acc[NB];
#pragma unroll
        for (int b = 0; b < NB; ++b) {
            const float4* fb = (const float4*)(fs + (size_t)(b0 + b) * (Ad * Od));
            const float4 v4 = *(const float4*)&v_lds[b][oq * 4];
            float s = 0.f;
#pragma unroll
            for (int r = 0; r < 4; ++r) {
                const int a = ag + 8 * r;
                const float4 f4 = fb[a * 32 + oq];
                float d = f4.x * v4.x;
                d = fmaf(f4.y, v4.y, d);
                d = fmaf(f4.z, v4.z, d);
                d = fmaf(f4.w, v4.w, d);
                s = fmaf(q_lds[b][a], d, s);
            }
            acc[b] = s;
        }
        // wave butterfly reduce each b, lane 0 stores per-wave partial
        const int lane = tid & 63;
        const int wv = tid >> 6;
#pragma unroll
        for (int b = 0; b < NB; ++b) {
            float s = acc[b];
#pragma unroll
            for (int d = 32; d >= 1; d >>= 1) s += __shfl_xor(s, d);
            acc[b] = s;
        }
        if (lane == 0) {
#pragma unroll
            for (int b = 0; b < NB; ++b) red_lds[b][wv] = acc[b];
        }
    }
    __syncthreads();

    // ---- final: out[b] = sum of 4 wave partials + bias[b] ----
    if (tid < NB) {
        out[b0 + tid] = red_lds[tid][0] + red_lds[tid][1] +
                        red_lds[tid][2] + red_lds[tid][3] + bias_lds[tid];
    }
}

extern "C" void kernel_launch(void* const* d_in, const int* in_sizes, int n_in,
                              void* d_out, int out_size, void* d_ws, size_t ws_size,
                              hipStream_t stream) {
    const float* qv  = (const float*)d_in[0];
    const float* st  = (const float*)d_in[1];
    const float* fs  = (const float*)d_in[2];
    const float* Wq1 = (const float*)d_in[3];
    const float* bq1 = (const float*)d_in[4];
    const float* Wq2 = (const float*)d_in[5];
    const float* bq2 = (const float*)d_in[6];
    const float* Wk  = (const float*)d_in[7];
    const float* bk  = (const float*)d_in[8];
    const float* Wc1 = (const float*)d_in[9];
    const float* bc1 = (const float*)d_in[10];
    const float* Wc2 = (const float*)d_in[11];
    const float* bc2 = (const float*)d_in[12];
    float* out = (float*)d_out;

    float* WkT   = (float*)d_ws;            // 64*128 floats
    float* bkSum = WkT + QDd * Od;          // 64 floats

    qatten_prep<<<32, 256, 0, stream>>>(Wk, bk, WkT, bkSum);
    qatten_fused<<<1024, 256, 0, stream>>>(qv, st, fs, Wq1, bq1, Wq2, bq2,
                                           Wc1, bc1, Wc2, bc2, WkT, bkSum, out);
}